// Round 16
// baseline (310.520 us; speedup 1.0000x reference)
//
#include <hip/hip_runtime.h>
#include <stdint.h>

#define BATCH  256
#define CDIM   2048
#define HW     49
#define NTOK   50
#define MROWS  (BATCH * NTOK)   // 12800
#define ODIM   1024
#define NHEADS 32

typedef __attribute__((ext_vector_type(8))) short short8;
typedef __attribute__((ext_vector_type(4))) float f32x4;
typedef unsigned short u16;
typedef unsigned int   u32;

__device__ __forceinline__ float bf2f(u16 u) {
  union { u32 i; float f; } v; v.i = ((u32)u) << 16; return v.f;
}
__device__ __forceinline__ u16 f2bf(float f) {
  union { float f; u32 i; } v; v.f = f;
  u32 r = v.i + 0x7fffu + ((v.i >> 16) & 1u);   // round-to-nearest-even
  return (u16)(r >> 16);
}

// async global->LDS, 16 bytes per lane (wave-uniform base + lane*16 dest)
__device__ __forceinline__ void async16(const void* g, void* l) {
  __builtin_amdgcn_global_load_lds(
      (const __attribute__((address_space(1))) u32*)g,
      (__attribute__((address_space(3))) u32*)l, 16, 0, 0);
}

// barrier that is ALSO a compiler memory fence (R5 lesson)
#define BARRIER() asm volatile("s_barrier" ::: "memory")

// ---------------- fused fp32->bf16 weight convert + token prep ----------------
__global__ __launch_bounds__(256) void cvt_prep_kernel(
    const float* __restrict__ Wv, u16* __restrict__ WvB, int n4a,
    const float* __restrict__ Wc, u16* __restrict__ WcB, int n4b,
    const float* __restrict__ x, const float* __restrict__ pos,
    u16* __restrict__ T, int nCvt) {
  if (blockIdx.x < (unsigned)nCvt) {
    int i = blockIdx.x * 256 + threadIdx.x;
    const float* src; u16* dst; int idx;
    if (i < n4a) { src = Wv; dst = WvB; idx = i; }
    else {
      idx = i - n4a;
      if (idx >= n4b) return;
      src = Wc; dst = WcB;
    }
    float4 v = reinterpret_cast<const float4*>(src)[idx];
    ushort4 o;
    o.x = f2bf(v.x); o.y = f2bf(v.y); o.z = f2bf(v.z); o.w = f2bf(v.w);
    reinterpret_cast<ushort4*>(dst)[idx] = o;
    return;
  }
  const int blk = blockIdx.x - nCvt;
  const int b  = blk >> 5;             // 32 chunks of 64 channels
  const int c0 = (blk & 31) * 64;
  __shared__ float xs[64 * HW];
  __shared__ float mean[64];
  const float* src = x + ((size_t)b * CDIM + c0) * HW;  // 3136 floats
  for (int i = threadIdx.x; i < 64 * HW / 4; i += 256)
    reinterpret_cast<float4*>(xs)[i] = reinterpret_cast<const float4*>(src)[i];
  __syncthreads();
  if (threadIdx.x < 64) {
    float s = 0.f;
#pragma unroll
    for (int j = 0; j < HW; j++) s += xs[threadIdx.x * HW + j];
    mean[threadIdx.x] = s * (1.0f / 49.0f);
  }
  __syncthreads();
  for (int wi = threadIdx.x; wi < NTOK * 8; wi += 256) {
    const int n = wi >> 3;
    const int g = (wi & 7) * 8;
    alignas(16) u16 ov[8];
#pragma unroll
    for (int u = 0; u < 8; u++) {
      const int c = g + u;
      float val = (n == 0) ? mean[c] : xs[c * HW + (n - 1)];
      val += pos[n * CDIM + c0 + c];
      ov[u] = f2bf(val);
    }
    *reinterpret_cast<uint4*>(&T[((size_t)b * NTOK + n) * CDIM + c0 + g]) =
        *reinterpret_cast<const uint4*>(ov);
  }
}

// ---------------- 128x128 GEMM (B^T), 3 blocks/CU, MT m-tiles per block -----
// Register law (R4/R12/R13): spill iff arch+AGPR > 512/WPE. WPE=3 -> 170;
// this kernel needs 84 arch + 64 acc = 148. WPE>=4 spills. 128^2@256thr@3/CU
// is the max-TLP shape of this family.
// MT=1: GEMM1 (grid 1600, smooth 2.08 rounds, proven 127 us R11/R14).
// MT=2: GEMM2 (grid 400 <= 768 slots -> single round; 2 sequential m-tiles,
//       B-panel re-served from L2 on second pass). Fixes R11's 800/768
//       quantization without leaving the proven gemm128 regime.
// LDS hazard for mt-loop: last K-tile ends lgkm(0)-drain + fenced BARRIER
// after MFMA -> all reads done; epilogue touches only global -> next mt may
// stage immediately (same ledger as inter-K-tile).
template<int OUT_BF16, int MT>
__global__ __launch_bounds__(256, 3)
void gemm128(const u16* __restrict__ A, const u16* __restrict__ Bm,
             const float* __restrict__ bias, void* __restrict__ Cout,
             int M, int N, int K, int nbx) {
  __shared__ __align__(16) u16 smem[16384];   // As[128][64] | Bs[128][64]

  const int NK = K >> 6;
  const int t = threadIdx.x;
  const int lane = t & 63;
  const int wid = t >> 6;
  const int wm = wid >> 1;          // 0..1
  const int wn = wid & 1;           // 0..1

  // bijective XCD swizzle (gridDim.x % 8 == 0)
  const int nwg = gridDim.x;
  const int cpx = nwg >> 3;
  const int orig = blockIdx.x;
  const int swz = (orig & 7) * cpx + (orig >> 3);
  const int bx = swz % nbx;
  const int by = swz / nbx;
  const int n0 = bx * 128;
  const int mbase = by * (128 * MT);

  // staging source (pre-swizzled octet so linear LDS dest = swizzled layout)
  const int tr  = t >> 3;                    // 0..31
  const int to8 = ((t & 7) ^ (tr & 7)) << 3;
  const int t8  = t << 3;
  const u16* pB0 = Bm + (size_t)(n0 + tr) * K + to8;

  // ds_read offsets (elements), granule g = kk*4+hi XORed with row&7
  const int lr = lane & 15, hi = lane >> 4;
  const int sx = lr & 7;
  const int aK0 = ((wm * 64 + lr) << 6) + (((0 + hi) ^ sx) << 3);
  const int aK1 = ((wm * 64 + lr) << 6) + (((4 + hi) ^ sx) << 3);
  const int bK0 = 8192 + ((wn * 64 + lr) << 6) + (((0 + hi) ^ sx) << 3);
  const int bK1 = 8192 + ((wn * 64 + lr) << 6) + (((4 + hi) ^ sx) << 3);

  for (int mt = 0; mt < MT; ++mt) {
    const int m0 = mbase + mt * 128;
    const u16* pA0 = A + (size_t)(m0 + tr) * K + to8;

    f32x4 acc[4][4] = {};
    short8 a[4][2], b[4][2];

    for (int kt = 0; kt < NK; ++kt) {
#pragma unroll
      for (int c = 0; c < 4; ++c)
        async16(pA0 + (size_t)(c * 32) * K + kt * 64, &smem[c * 2048 + t8]);
#pragma unroll
      for (int c = 0; c < 4; ++c)
        async16(pB0 + (size_t)(c * 32) * K + kt * 64, &smem[8192 + c * 2048 + t8]);
      asm volatile("s_waitcnt vmcnt(0)" ::: "memory");
      BARRIER();

#pragma unroll
      for (int f = 0; f < 4; ++f) {
        a[f][0] = *(const short8*)&smem[aK0 + f * 1024];
        a[f][1] = *(const short8*)&smem[aK1 + f * 1024];
      }
#pragma unroll
      for (int f = 0; f < 4; ++f) {
        b[f][0] = *(const short8*)&smem[bK0 + f * 1024];
        b[f][1] = *(const short8*)&smem[bK1 + f * 1024];
      }
      asm volatile("s_waitcnt lgkmcnt(0)" ::: "memory");
      __builtin_amdgcn_sched_barrier(0);
      __builtin_amdgcn_s_setprio(1);
#pragma unroll
      for (int fm = 0; fm < 4; ++fm)
#pragma unroll
        for (int fn = 0; fn < 4; ++fn) {
          acc[fm][fn] = __builtin_amdgcn_mfma_f32_16x16x32_bf16(
              a[fm][0], b[fn][0], acc[fm][fn], 0, 0, 0);
          acc[fm][fn] = __builtin_amdgcn_mfma_f32_16x16x32_bf16(
              a[fm][1], b[fn][1], acc[fm][fn], 0, 0, 0);
        }
      __builtin_amdgcn_s_setprio(0);
      BARRIER();
    }

    // epilogue: C/D layout col=lane&15, row=(lane>>4)*4+j  [m89/m91]
    const int erow = hi * 4;
#pragma unroll
    for (int fm = 0; fm < 4; ++fm) {
#pragma unroll
      for (int fn = 0; fn < 4; ++fn) {
        const int cg = n0 + wn * 64 + fn * 16 + lr;
        const float bb = bias[cg];
        const int rbase = m0 + wm * 64 + fm * 16 + erow;
#pragma unroll
        for (int jr = 0; jr < 4; ++jr) {
          const float val = acc[fm][fn][jr] + bb;
          if (OUT_BF16)
            ((u16*)Cout)[(size_t)(rbase + jr) * N + cg] = f2bf(val);
          else
            ((float*)Cout)[(size_t)(rbase + jr) * N + cg] = val;
        }
      }
    }
  }
}

// ---------------- token-0 attention, per (b,h), in-place on V ----------------
__global__ __launch_bounds__(64) void attn0_kernel(u16* __restrict__ V) {
  const int b = blockIdx.x, h = blockIdx.y;
  __shared__ __align__(16) u16 vt[NTOK * 64];
  __shared__ float pb[64];
  const int t = threadIdx.x;
  u16* base = V + (size_t)b * NTOK * CDIM + h * 64;
  for (int idx = t; idx < NTOK * 8; idx += 64) {
    const int m = idx >> 3, g = (idx & 7) * 8;
    *reinterpret_cast<uint4*>(&vt[m * 64 + g]) =
        *reinterpret_cast<const uint4*>(base + (size_t)m * CDIM + g);
  }
  __syncthreads();
  const float qd = bf2f(vt[t]);
  float s_own = -1e30f;
  for (int m = 0; m < NTOK; m++) {
    float p = qd * bf2f(vt[m * 64 + t]);
#pragma unroll
    for (int off = 32; off; off >>= 1) p += __shfl_xor(p, off);
    if (t == m) s_own = p * 0.125f;
  }
  float mx = s_own;
#pragma unroll
  for (int off = 32; off; off >>= 1) mx = fmaxf(mx, __shfl_xor(mx, off));
  const float e = (t < NTOK) ? __expf(s_own - mx) : 0.f;
  float Z = e;
#pragma unroll
  for (int off = 32; off; off >>= 1) Z += __shfl_xor(Z, off);
  pb[t] = e / Z;
  __syncthreads();
  float acc = 0.f;
  for (int m = 0; m < NTOK; m++) acc += pb[m] * bf2f(vt[m * 64 + t]);
  base[t] = f2bf(acc);
}

// ---------------- launch ----------------
extern "C" void kernel_launch(void* const* d_in, const int* in_sizes, int n_in,
                              void* d_out, int out_size, void* d_ws, size_t ws_size,
                              hipStream_t stream) {
  const float* x   = (const float*)d_in[0];
  const float* pos = (const float*)d_in[1];
  const float* Wv  = (const float*)d_in[2];
  const float* bv  = (const float*)d_in[3];
  const float* Wc  = (const float*)d_in[4];
  const float* bc  = (const float*)d_in[5];
  float* out = (float*)d_out;

  u16* T   = (u16*)d_ws;                        // [12800][2048] bf16
  u16* V   = T   + (size_t)MROWS * CDIM;        // [12800][2048] bf16
  u16* WvB = V   + (size_t)MROWS * CDIM;        // [2048][2048]  bf16
  u16* WcB = WvB + (size_t)CDIM * CDIM;         // [1024][2048]  bf16

  {
    int n4a = CDIM * CDIM / 4;                  // 1048576
    int n4b = ODIM * CDIM / 4;                  // 524288
    int nCvt = (n4a + n4b + 255) / 256;         // 6144
    cvt_prep_kernel<<<nCvt + BATCH * 32, 256, 0, stream>>>(
        Wv, WvB, n4a, Wc, WcB, n4b, x, pos, T, nCvt);
  }

  // GEMM1: 128^2, MT=1, grid 1600, 3 blocks/CU (proven 127 us)
  gemm128<1, 1><<<(MROWS / 128) * (CDIM / 128), 256, 0, stream>>>(
      T, WvB, bv, V, MROWS, CDIM, CDIM, CDIM / 128);

  attn0_kernel<<<dim3(BATCH, NHEADS), 64, 0, stream>>>(V);

  // GEMM2: 128^2, MT=2, grid 50x8=400 <= 768 slots -> single round
  gemm128<0, 2><<<(MROWS / 256) * (ODIM / 128), 256, 0, stream>>>(
      V, WcB, bc, out, MROWS, ODIM, CDIM, ODIM / 128);
}

// Round 17
// 300.614 us; speedup vs baseline: 1.0330x; 1.0330x over previous
//
#include <hip/hip_runtime.h>
#include <stdint.h>

#define BATCH  256
#define CDIM   2048
#define HW     49
#define NTOK   50
#define MROWS  (BATCH * NTOK)   // 12800
#define ODIM   1024
#define NHEADS 32

typedef __attribute__((ext_vector_type(8))) short short8;
typedef __attribute__((ext_vector_type(4))) float f32x4;
typedef unsigned short u16;
typedef unsigned int   u32;

__device__ __forceinline__ float bf2f(u16 u) {
  union { u32 i; float f; } v; v.i = ((u32)u) << 16; return v.f;
}
__device__ __forceinline__ u16 f2bf(float f) {
  union { float f; u32 i; } v; v.f = f;
  u32 r = v.i + 0x7fffu + ((v.i >> 16) & 1u);   // round-to-nearest-even
  return (u16)(r >> 16);
}

// async global->LDS, 16 bytes per lane (wave-uniform base + lane*16 dest)
__device__ __forceinline__ void async16(const void* g, void* l) {
  __builtin_amdgcn_global_load_lds(
      (const __attribute__((address_space(1))) u32*)g,
      (__attribute__((address_space(3))) u32*)l, 16, 0, 0);
}

// barrier that is ALSO a compiler memory fence (R5 lesson)
#define BARRIER() asm volatile("s_barrier" ::: "memory")

// ---------------- fused fp32->bf16 weight convert + token prep ----------------
__global__ __launch_bounds__(256) void cvt_prep_kernel(
    const float* __restrict__ Wv, u16* __restrict__ WvB, int n4a,
    const float* __restrict__ Wc, u16* __restrict__ WcB, int n4b,
    const float* __restrict__ x, const float* __restrict__ pos,
    u16* __restrict__ T, int nCvt) {
  if (blockIdx.x < (unsigned)nCvt) {
    int i = blockIdx.x * 256 + threadIdx.x;
    const float* src; u16* dst; int idx;
    if (i < n4a) { src = Wv; dst = WvB; idx = i; }
    else {
      idx = i - n4a;
      if (idx >= n4b) return;
      src = Wc; dst = WcB;
    }
    float4 v = reinterpret_cast<const float4*>(src)[idx];
    ushort4 o;
    o.x = f2bf(v.x); o.y = f2bf(v.y); o.z = f2bf(v.z); o.w = f2bf(v.w);
    reinterpret_cast<ushort4*>(dst)[idx] = o;
    return;
  }
  const int blk = blockIdx.x - nCvt;
  const int b  = blk >> 5;             // 32 chunks of 64 channels
  const int c0 = (blk & 31) * 64;
  __shared__ float xs[64 * HW];
  __shared__ float mean[64];
  const float* src = x + ((size_t)b * CDIM + c0) * HW;  // 3136 floats
  for (int i = threadIdx.x; i < 64 * HW / 4; i += 256)
    reinterpret_cast<float4*>(xs)[i] = reinterpret_cast<const float4*>(src)[i];
  __syncthreads();
  if (threadIdx.x < 64) {
    float s = 0.f;
#pragma unroll
    for (int j = 0; j < HW; j++) s += xs[threadIdx.x * HW + j];
    mean[threadIdx.x] = s * (1.0f / 49.0f);
  }
  __syncthreads();
  for (int wi = threadIdx.x; wi < NTOK * 8; wi += 256) {
    const int n = wi >> 3;
    const int g = (wi & 7) * 8;
    alignas(16) u16 ov[8];
#pragma unroll
    for (int u = 0; u < 8; u++) {
      const int c = g + u;
      float val = (n == 0) ? mean[c] : xs[c * HW + (n - 1)];
      val += pos[n * CDIM + c0 + c];
      ov[u] = f2bf(val);
    }
    *reinterpret_cast<uint4*>(&T[((size_t)b * NTOK + n) * CDIM + c0 + g]) =
        *reinterpret_cast<const uint4*>(ov);
  }
}

// ---------------- GEMM1: 128x128, 3 blocks/CU, bf16 out (proven 127 us) -----
// Non-template plain function: R13 showed co-compiled template instantiations
// can perturb each other's regalloc (VGPR 84 -> 64 + 493MB scratch). Distinct
// named functions are the guard (rule #19).
__global__ __launch_bounds__(256, 3)
void gemm1_kernel(const u16* __restrict__ A, const u16* __restrict__ Bm,
                  const float* __restrict__ bias, u16* __restrict__ Cout,
                  int M, int N, int K, int nbx) {
  __shared__ __align__(16) u16 smem[16384];   // As[128][64] | Bs[128][64]

  const int NK = K >> 6;
  const int t = threadIdx.x;
  const int lane = t & 63;
  const int wid = t >> 6;
  const int wm = wid >> 1;
  const int wn = wid & 1;

  const int nwg = gridDim.x;
  const int cpx = nwg >> 3;
  const int orig = blockIdx.x;
  const int swz = (orig & 7) * cpx + (orig >> 3);
  const int bx = swz % nbx;
  const int by = swz / nbx;
  const int m0 = by * 128, n0 = bx * 128;

  const int tr  = t >> 3;
  const int to8 = ((t & 7) ^ (tr & 7)) << 3;
  const int t8  = t << 3;
  const u16* pA0 = A  + (size_t)(m0 + tr) * K + to8;
  const u16* pB0 = Bm + (size_t)(n0 + tr) * K + to8;

  const int lr = lane & 15, hi = lane >> 4;
  const int sx = lr & 7;
  const int aK0 = ((wm * 64 + lr) << 6) + (((0 + hi) ^ sx) << 3);
  const int aK1 = ((wm * 64 + lr) << 6) + (((4 + hi) ^ sx) << 3);
  const int bK0 = 8192 + ((wn * 64 + lr) << 6) + (((0 + hi) ^ sx) << 3);
  const int bK1 = 8192 + ((wn * 64 + lr) << 6) + (((4 + hi) ^ sx) << 3);

  f32x4 acc[4][4] = {};
  short8 a[4][2], b[4][2];

  for (int kt = 0; kt < NK; ++kt) {
#pragma unroll
    for (int c = 0; c < 4; ++c)
      async16(pA0 + (size_t)(c * 32) * K + kt * 64, &smem[c * 2048 + t8]);
#pragma unroll
    for (int c = 0; c < 4; ++c)
      async16(pB0 + (size_t)(c * 32) * K + kt * 64, &smem[8192 + c * 2048 + t8]);
    asm volatile("s_waitcnt vmcnt(0)" ::: "memory");
    BARRIER();

#pragma unroll
    for (int f = 0; f < 4; ++f) {
      a[f][0] = *(const short8*)&smem[aK0 + f * 1024];
      a[f][1] = *(const short8*)&smem[aK1 + f * 1024];
    }
#pragma unroll
    for (int f = 0; f < 4; ++f) {
      b[f][0] = *(const short8*)&smem[bK0 + f * 1024];
      b[f][1] = *(const short8*)&smem[bK1 + f * 1024];
    }
    asm volatile("s_waitcnt lgkmcnt(0)" ::: "memory");
    __builtin_amdgcn_sched_barrier(0);
    __builtin_amdgcn_s_setprio(1);
#pragma unroll
    for (int fm = 0; fm < 4; ++fm)
#pragma unroll
      for (int fn = 0; fn < 4; ++fn) {
        acc[fm][fn] = __builtin_amdgcn_mfma_f32_16x16x32_bf16(
            a[fm][0], b[fn][0], acc[fm][fn], 0, 0, 0);
        acc[fm][fn] = __builtin_amdgcn_mfma_f32_16x16x32_bf16(
            a[fm][1], b[fn][1], acc[fm][fn], 0, 0, 0);
      }
    __builtin_amdgcn_s_setprio(0);
    BARRIER();
  }

  const int erow = hi * 4;
#pragma unroll
  for (int fm = 0; fm < 4; ++fm) {
#pragma unroll
    for (int fn = 0; fn < 4; ++fn) {
      const int cg = n0 + wn * 64 + fn * 16 + lr;
      const float bb = bias[cg];
      const int rbase = m0 + wm * 64 + fm * 16 + erow;
#pragma unroll
      for (int jr = 0; jr < 4; ++jr)
        Cout[(size_t)(rbase + jr) * N + cg] = f2bf(acc[fm][fn][jr] + bb);
    }
  }
}

// ---------------- GEMM2: 256x256 2-phase, fp32 out (proven ~92 us R8/R10) ---
__global__ __launch_bounds__(512, 2)
void gemm2_kernel(const u16* __restrict__ A, const u16* __restrict__ Bm,
                  const float* __restrict__ bias, float* __restrict__ Cout,
                  int M, int N, int K, int nbx) {
  __shared__ __align__(16) u16 smem[65536];   // 128 KiB

  const int NK = K >> 6;
  const int t = threadIdx.x;
  const int lane = t & 63;
  const int wid = t >> 6;
  const int wm = wid >> 2;
  const int wn = wid & 3;

  const int nwg = gridDim.x;
  const int cpx = nwg >> 3;
  const int orig = blockIdx.x;
  const int swz = (orig & 7) * cpx + (orig >> 3);
  const int bx = swz % nbx;
  const int by = swz / nbx;
  const int m0 = by * 256, n0 = bx * 256;

  const int tr  = t >> 3;
  const int to8 = ((t & 7) ^ (tr & 7)) << 3;
  const int t8  = t << 3;
  const u16* pA0 = A  + (size_t)(m0 + tr) * K + to8;
  const u16* pB0 = Bm + (size_t)(n0 + tr) * K + to8;

  const int lr = lane & 15, hi = lane >> 4;
  const int sx = lr & 7;
  const int aK0 = ((wm * 128 + lr) << 6) + (((0 + hi) ^ sx) << 3);
  const int aK1 = ((wm * 128 + lr) << 6) + (((4 + hi) ^ sx) << 3);
  const int bK0 = 16384 + ((wn * 64 + lr) << 6) + (((0 + hi) ^ sx) << 3);
  const int bK1 = 16384 + ((wn * 64 + lr) << 6) + (((4 + hi) ^ sx) << 3);

  f32x4 acc[8][4] = {};
  short8 a[4][2], b[4][2];

  auto STG = [&](int kti, int isB, int h) {
    if (kti < NK) {
      const u16* g = (isB ? pB0 : pA0) + (size_t)(h * 128) * K + kti * 64;
      u16* l = &smem[((kti & 1) << 15) + (isB << 14) + (h << 13) + t8];
      async16(g, l);
      async16(g + (size_t)64 * K, l + 4096);
    }
  };

#define MFMA4x2(BN0, ACCM, ACCN)                                              \
  _Pragma("unroll")                                                           \
  for (int fm = 0; fm < 4; ++fm) {                                            \
    _Pragma("unroll")                                                         \
    for (int fn = 0; fn < 2; ++fn) {                                          \
      acc[(ACCM) + fm][(ACCN) + fn] = __builtin_amdgcn_mfma_f32_16x16x32_bf16(\
          a[fm][0], b[(BN0) + fn][0], acc[(ACCM) + fm][(ACCN) + fn], 0, 0, 0);\
      acc[(ACCM) + fm][(ACCN) + fn] = __builtin_amdgcn_mfma_f32_16x16x32_bf16(\
          a[fm][1], b[(BN0) + fn][1], acc[(ACCM) + fm][(ACCN) + fn], 0, 0, 0);\
    }                                                                         \
  }

  STG(0, 0, 0); STG(0, 0, 1); STG(0, 1, 0); STG(0, 1, 1);
  asm volatile("s_waitcnt vmcnt(0)" ::: "memory");
  BARRIER();

  for (int j = 0; j < NK; ++j) {
    const u16* sa = &smem[(j & 1) << 15];

    // ---- Phase A: a-lo + b-lo + b-hi; stage ALL of tile j+1 ----
#pragma unroll
    for (int f = 0; f < 4; ++f) {
      a[f][0] = *(const short8*)&sa[aK0 + f * 1024];
      a[f][1] = *(const short8*)&sa[aK1 + f * 1024];
    }
#pragma unroll
    for (int f = 0; f < 4; ++f) {
      b[f][0] = *(const short8*)&sa[bK0 + f * 1024];
      b[f][1] = *(const short8*)&sa[bK1 + f * 1024];
    }
    STG(j + 1, 0, 0); STG(j + 1, 0, 1); STG(j + 1, 1, 0); STG(j + 1, 1, 1);
    BARRIER();
    asm volatile("s_waitcnt lgkmcnt(0)" ::: "memory");
    __builtin_amdgcn_sched_barrier(0);
    __builtin_amdgcn_s_setprio(1);
    MFMA4x2(0, 0, 0);
    MFMA4x2(2, 0, 2);
    __builtin_amdgcn_s_setprio(0);
    BARRIER();

    // ---- Phase B: a-hi (overwrites a) ----
#pragma unroll
    for (int f = 0; f < 4; ++f) {
      a[f][0] = *(const short8*)&sa[aK0 + (4 + f) * 1024];
      a[f][1] = *(const short8*)&sa[aK1 + (4 + f) * 1024];
    }
    BARRIER();
    asm volatile("s_waitcnt lgkmcnt(0)" ::: "memory");
    __builtin_amdgcn_sched_barrier(0);
    __builtin_amdgcn_s_setprio(1);
    MFMA4x2(2, 4, 2);
    MFMA4x2(0, 4, 0);
    __builtin_amdgcn_s_setprio(0);
    asm volatile("s_waitcnt vmcnt(0)" ::: "memory");
    BARRIER();
  }

  const int erow = hi * 4;
#pragma unroll
  for (int fm = 0; fm < 8; ++fm) {
#pragma unroll
    for (int fn = 0; fn < 4; ++fn) {
      const int cg = n0 + wn * 64 + fn * 16 + lr;
      const float bb = bias[cg];
      const int rbase = m0 + wm * 128 + fm * 16 + erow;
#pragma unroll
      for (int jr = 0; jr < 4; ++jr)
        Cout[(size_t)(rbase + jr) * N + cg] = acc[fm][fn][jr] + bb;
    }
  }
#undef MFMA4x2
}

// ---------------- token-0 attention, per (b,h), in-place on V ----------------
__global__ __launch_bounds__(64) void attn0_kernel(u16* __restrict__ V) {
  const int b = blockIdx.x, h = blockIdx.y;
  __shared__ __align__(16) u16 vt[NTOK * 64];
  __shared__ float pb[64];
  const int t = threadIdx.x;
  u16* base = V + (size_t)b * NTOK * CDIM + h * 64;
  for (int idx = t; idx < NTOK * 8; idx += 64) {
    const int m = idx >> 3, g = (idx & 7) * 8;
    *reinterpret_cast<uint4*>(&vt[m * 64 + g]) =
        *reinterpret_cast<const uint4*>(base + (size_t)m * CDIM + g);
  }
  __syncthreads();
  const float qd = bf2f(vt[t]);
  float s_own = -1e30f;
  for (int m = 0; m < NTOK; m++) {
    float p = qd * bf2f(vt[m * 64 + t]);
#pragma unroll
    for (int off = 32; off; off >>= 1) p += __shfl_xor(p, off);
    if (t == m) s_own = p * 0.125f;
  }
  float mx = s_own;
#pragma unroll
  for (int off = 32; off; off >>= 1) mx = fmaxf(mx, __shfl_xor(mx, off));
  const float e = (t < NTOK) ? __expf(s_own - mx) : 0.f;
  float Z = e;
#pragma unroll
  for (int off = 32; off; off >>= 1) Z += __shfl_xor(Z, off);
  pb[t] = e / Z;
  __syncthreads();
  float acc = 0.f;
  for (int m = 0; m < NTOK; m++) acc += pb[m] * bf2f(vt[m * 64 + t]);
  base[t] = f2bf(acc);
}

// ---------------- launch ----------------
extern "C" void kernel_launch(void* const* d_in, const int* in_sizes, int n_in,
                              void* d_out, int out_size, void* d_ws, size_t ws_size,
                              hipStream_t stream) {
  const float* x   = (const float*)d_in[0];
  const float* pos = (const float*)d_in[1];
  const float* Wv  = (const float*)d_in[2];
  const float* bv  = (const float*)d_in[3];
  const float* Wc  = (const float*)d_in[4];
  const float* bc  = (const float*)d_in[5];
  float* out = (float*)d_out;

  u16* T   = (u16*)d_ws;                        // [12800][2048] bf16
  u16* V   = T   + (size_t)MROWS * CDIM;        // [12800][2048] bf16
  u16* WvB = V   + (size_t)MROWS * CDIM;        // [2048][2048]  bf16
  u16* WcB = WvB + (size_t)CDIM * CDIM;         // [1024][2048]  bf16

  {
    int n4a = CDIM * CDIM / 4;                  // 1048576
    int n4b = ODIM * CDIM / 4;                  // 524288
    int nCvt = (n4a + n4b + 255) / 256;         // 6144
    cvt_prep_kernel<<<nCvt + BATCH * 32, 256, 0, stream>>>(
        Wv, WvB, n4a, Wc, WcB, n4b, x, pos, T, nCvt);
  }

  // GEMM1: 128^2 tile, grid 1600, 3 blocks/CU (proven 127 us)
  gemm1_kernel<<<(MROWS / 128) * (CDIM / 128), 256, 0, stream>>>(
      T, WvB, bv, V, MROWS, CDIM, CDIM, CDIM / 128);

  attn0_kernel<<<dim3(BATCH, NHEADS), 64, 0, stream>>>(V);

  // GEMM2: 256^2 tile, grid 200 <= 256 slots, single round (proven ~92 us)
  gemm2_kernel<<<(MROWS / 256) * (ODIM / 256), 512, 0, stream>>>(
      V, WcB, bc, out, MROWS, ODIM, CDIM, ODIM / 256);
}

// Round 18
// 287.868 us; speedup vs baseline: 1.0787x; 1.0443x over previous
//
#include <hip/hip_runtime.h>
#include <stdint.h>

#define BATCH  256
#define CDIM   2048
#define HW     49
#define NTOK   50
#define MROWS  (BATCH * NTOK)   // 12800
#define ODIM   1024
#define NHEADS 32

typedef __attribute__((ext_vector_type(8))) short short8;
typedef __attribute__((ext_vector_type(4))) float f32x4;
typedef unsigned short u16;
typedef unsigned int   u32;

__device__ __forceinline__ float bf2f(u16 u) {
  union { u32 i; float f; } v; v.i = ((u32)u) << 16; return v.f;
}
__device__ __forceinline__ u16 f2bf(float f) {
  union { float f; u32 i; } v; v.f = f;
  u32 r = v.i + 0x7fffu + ((v.i >> 16) & 1u);   // round-to-nearest-even
  return (u16)(r >> 16);
}

// async global->LDS, 16 bytes per lane (wave-uniform base + lane*16 dest)
__device__ __forceinline__ void async16(const void* g, void* l) {
  __builtin_amdgcn_global_load_lds(
      (const __attribute__((address_space(1))) u32*)g,
      (__attribute__((address_space(3))) u32*)l, 16, 0, 0);
}

// barrier that is ALSO a compiler memory fence (R5 lesson)
#define BARRIER() asm volatile("s_barrier" ::: "memory")

// ---------------- fused fp32->bf16 weight convert + token prep ----------------
__global__ __launch_bounds__(256) void cvt_prep_kernel(
    const float* __restrict__ Wv, u16* __restrict__ WvB, int n4a,
    const float* __restrict__ Wc, u16* __restrict__ WcB, int n4b,
    const float* __restrict__ x, const float* __restrict__ pos,
    u16* __restrict__ T, int nCvt) {
  if (blockIdx.x < (unsigned)nCvt) {
    int i = blockIdx.x * 256 + threadIdx.x;
    const float* src; u16* dst; int idx;
    if (i < n4a) { src = Wv; dst = WvB; idx = i; }
    else {
      idx = i - n4a;
      if (idx >= n4b) return;
      src = Wc; dst = WcB;
    }
    float4 v = reinterpret_cast<const float4*>(src)[idx];
    ushort4 o;
    o.x = f2bf(v.x); o.y = f2bf(v.y); o.z = f2bf(v.z); o.w = f2bf(v.w);
    reinterpret_cast<ushort4*>(dst)[idx] = o;
    return;
  }
  const int blk = blockIdx.x - nCvt;
  const int b  = blk >> 5;             // 32 chunks of 64 channels
  const int c0 = (blk & 31) * 64;
  __shared__ float xs[64 * HW];
  __shared__ float mean[64];
  const float* src = x + ((size_t)b * CDIM + c0) * HW;  // 3136 floats
  for (int i = threadIdx.x; i < 64 * HW / 4; i += 256)
    reinterpret_cast<float4*>(xs)[i] = reinterpret_cast<const float4*>(src)[i];
  __syncthreads();
  if (threadIdx.x < 64) {
    float s = 0.f;
#pragma unroll
    for (int j = 0; j < HW; j++) s += xs[threadIdx.x * HW + j];
    mean[threadIdx.x] = s * (1.0f / 49.0f);
  }
  __syncthreads();
  for (int wi = threadIdx.x; wi < NTOK * 8; wi += 256) {
    const int n = wi >> 3;
    const int g = (wi & 7) * 8;
    alignas(16) u16 ov[8];
#pragma unroll
    for (int u = 0; u < 8; u++) {
      const int c = g + u;
      float val = (n == 0) ? mean[c] : xs[c * HW + (n - 1)];
      val += pos[n * CDIM + c0 + c];
      ov[u] = f2bf(val);
    }
    *reinterpret_cast<uint4*>(&T[((size_t)b * NTOK + n) * CDIM + c0 + g]) =
        *reinterpret_cast<const uint4*>(ov);
  }
}

// ---------------- 256x256 GEMM (B^T): C = A*Bm^T + bias ---------------------
// R10-exact 2-phase kernel (best-known composition: total 288.2 us).
//   PhA: read a-lo(8)+b-lo(4)+b-hi(4); STG all of tile j+1 (8 ld); BAR;
//        lgkm0; 32 MFMA (Q(loM,loN)+Q(loM,hiN)); BAR
//   PhB: read a-hi(8) [overwrites a]; BAR; lgkm0;
//        32 MFMA (Q(hiM,hiN)+Q(hiM,loN)); vmcnt(0); BAR
// Note (R17 diagnosis): GEMM1 at this tile = 400 blocks @ 1/CU = 2 lockstep
// rounds (wave quantization) -> ~140 us regardless of schedule; GEMM2 =
// 200 blocks = single round ~92 us. gemm128-GEMM1 is 13 us faster alone but
// induces a reproducible +24 us on the following gemm256-GEMM2 (R14/R17) —
// so this pairing is the best-known total.
template<int OUT_BF16>
__global__ __launch_bounds__(512, 2)
void gemm256(const u16* __restrict__ A, const u16* __restrict__ Bm,
             const float* __restrict__ bias, void* __restrict__ Cout,
             int M, int N, int K, int nbx) {
  __shared__ __align__(16) u16 smem[65536];   // 128 KiB

  const int NK = K >> 6;
  const int t = threadIdx.x;
  const int lane = t & 63;
  const int wid = t >> 6;
  const int wm = wid >> 2;          // 0..1
  const int wn = wid & 3;           // 0..3

  // bijective XCD swizzle (gridDim.x % 8 == 0)
  const int nwg = gridDim.x;
  const int cpx = nwg >> 3;
  const int orig = blockIdx.x;
  const int swz = (orig & 7) * cpx + (orig >> 3);
  const int bx = swz % nbx;
  const int by = swz / nbx;
  const int m0 = by * 256, n0 = bx * 256;

  // staging source (pre-swizzled octet so linear LDS dest = swizzled layout)
  const int tr  = t >> 3;
  const int to8 = ((t & 7) ^ (tr & 7)) << 3;
  const int t8  = t << 3;
  const u16* pA0 = A  + (size_t)(m0 + tr) * K + to8;
  const u16* pB0 = Bm + (size_t)(n0 + tr) * K + to8;

  // ds_read offsets (elements), granule g=kk*4+hi XORed with row&7
  const int lr = lane & 15, hi = lane >> 4;
  const int sx = lr & 7;
  const int aK0 = ((wm * 128 + lr) << 6) + (((0 + hi) ^ sx) << 3);
  const int aK1 = ((wm * 128 + lr) << 6) + (((4 + hi) ^ sx) << 3);
  const int bK0 = 16384 + ((wn * 64 + lr) << 6) + (((0 + hi) ^ sx) << 3);
  const int bK1 = 16384 + ((wn * 64 + lr) << 6) + (((4 + hi) ^ sx) << 3);

  f32x4 acc[8][4] = {};
  short8 a[4][2], b[4][2];   // a: lo then hi (reused); b: lo AND hi live

  auto STG = [&](int kti, int isB, int h) {
    if (kti < NK) {
      const u16* g = (isB ? pB0 : pA0) + (size_t)(h * 128) * K + kti * 64;
      u16* l = &smem[((kti & 1) << 15) + (isB << 14) + (h << 13) + t8];
      async16(g, l);
      async16(g + (size_t)64 * K, l + 4096);
    }
  };

#define MFMA4x2(BN0, ACCM, ACCN)                                              \
  _Pragma("unroll")                                                           \
  for (int fm = 0; fm < 4; ++fm) {                                            \
    _Pragma("unroll")                                                         \
    for (int fn = 0; fn < 2; ++fn) {                                          \
      acc[(ACCM) + fm][(ACCN) + fn] = __builtin_amdgcn_mfma_f32_16x16x32_bf16(\
          a[fm][0], b[(BN0) + fn][0], acc[(ACCM) + fm][(ACCN) + fn], 0, 0, 0);\
      acc[(ACCM) + fm][(ACCN) + fn] = __builtin_amdgcn_mfma_f32_16x16x32_bf16(\
          a[fm][1], b[(BN0) + fn][1], acc[(ACCM) + fm][(ACCN) + fn], 0, 0, 0);\
    }                                                                         \
  }

  // prologue: stage all of tile 0
  STG(0, 0, 0); STG(0, 0, 1); STG(0, 1, 0); STG(0, 1, 1);
  asm volatile("s_waitcnt vmcnt(0)" ::: "memory");
  BARRIER();

  for (int j = 0; j < NK; ++j) {
    const u16* sa = &smem[(j & 1) << 15];

    // ---- Phase A: a-lo + b-lo + b-hi; stage ALL of tile j+1 ----
#pragma unroll
    for (int f = 0; f < 4; ++f) {
      a[f][0] = *(const short8*)&sa[aK0 + f * 1024];
      a[f][1] = *(const short8*)&sa[aK1 + f * 1024];
    }
#pragma unroll
    for (int f = 0; f < 4; ++f) {
      b[f][0] = *(const short8*)&sa[bK0 + f * 1024];
      b[f][1] = *(const short8*)&sa[bK1 + f * 1024];
    }
    STG(j + 1, 0, 0); STG(j + 1, 0, 1); STG(j + 1, 1, 0); STG(j + 1, 1, 1);
    BARRIER();
    asm volatile("s_waitcnt lgkmcnt(0)" ::: "memory");
    __builtin_amdgcn_sched_barrier(0);
    __builtin_amdgcn_s_setprio(1);
    MFMA4x2(0, 0, 0);
    MFMA4x2(2, 0, 2);
    __builtin_amdgcn_s_setprio(0);
    BARRIER();

    // ---- Phase B: a-hi (overwrites a) ----
#pragma unroll
    for (int f = 0; f < 4; ++f) {
      a[f][0] = *(const short8*)&sa[aK0 + (4 + f) * 1024];
      a[f][1] = *(const short8*)&sa[aK1 + (4 + f) * 1024];
    }
    BARRIER();
    asm volatile("s_waitcnt lgkmcnt(0)" ::: "memory");
    __builtin_amdgcn_sched_barrier(0);
    __builtin_amdgcn_s_setprio(1);
    MFMA4x2(2, 4, 2);
    MFMA4x2(0, 4, 0);
    __builtin_amdgcn_s_setprio(0);
    asm volatile("s_waitcnt vmcnt(0)" ::: "memory");
    BARRIER();
  }

  // epilogue: C/D layout col=lane&15, row=(lane>>4)*4+j  [m89/m91]
  const int erow = hi * 4;
#pragma unroll
  for (int fm = 0; fm < 8; ++fm) {
#pragma unroll
    for (int fn = 0; fn < 4; ++fn) {
      const int cg = n0 + wn * 64 + fn * 16 + lr;
      const float bb = bias[cg];
      const int rbase = m0 + wm * 128 + fm * 16 + erow;
#pragma unroll
      for (int jr = 0; jr < 4; ++jr) {
        const float val = acc[fm][fn][jr] + bb;
        if (OUT_BF16)
          ((u16*)Cout)[(size_t)(rbase + jr) * N + cg] = f2bf(val);
        else
          ((float*)Cout)[(size_t)(rbase + jr) * N + cg] = val;
      }
    }
  }
#undef MFMA4x2
}

// ---------------- token-0 attention, per (b,h), in-place on V ----------------
__global__ __launch_bounds__(64) void attn0_kernel(u16* __restrict__ V) {
  const int b = blockIdx.x, h = blockIdx.y;
  __shared__ __align__(16) u16 vt[NTOK * 64];
  __shared__ float pb[64];
  const int t = threadIdx.x;
  u16* base = V + (size_t)b * NTOK * CDIM + h * 64;
  for (int idx = t; idx < NTOK * 8; idx += 64) {
    const int m = idx >> 3, g = (idx & 7) * 8;
    *reinterpret_cast<uint4*>(&vt[m * 64 + g]) =
        *reinterpret_cast<const uint4*>(base + (size_t)m * CDIM + g);
  }
  __syncthreads();
  const float qd = bf2f(vt[t]);
  float s_own = -1e30f;
  for (int m = 0; m < NTOK; m++) {
    float p = qd * bf2f(vt[m * 64 + t]);
#pragma unroll
    for (int off = 32; off; off >>= 1) p += __shfl_xor(p, off);
    if (t == m) s_own = p * 0.125f;
  }
  float mx = s_own;
#pragma unroll
  for (int off = 32; off; off >>= 1) mx = fmaxf(mx, __shfl_xor(mx, off));
  const float e = (t < NTOK) ? __expf(s_own - mx) : 0.f;
  float Z = e;
#pragma unroll
  for (int off = 32; off; off >>= 1) Z += __shfl_xor(Z, off);
  pb[t] = e / Z;
  __syncthreads();
  float acc = 0.f;
  for (int m = 0; m < NTOK; m++) acc += pb[m] * bf2f(vt[m * 64 + t]);
  base[t] = f2bf(acc);
}

// ---------------- launch ----------------
extern "C" void kernel_launch(void* const* d_in, const int* in_sizes, int n_in,
                              void* d_out, int out_size, void* d_ws, size_t ws_size,
                              hipStream_t stream) {
  const float* x   = (const float*)d_in[0];
  const float* pos = (const float*)d_in[1];
  const float* Wv  = (const float*)d_in[2];
  const float* bv  = (const float*)d_in[3];
  const float* Wc  = (const float*)d_in[4];
  const float* bc  = (const float*)d_in[5];
  float* out = (float*)d_out;

  u16* T   = (u16*)d_ws;                        // [12800][2048] bf16
  u16* V   = T   + (size_t)MROWS * CDIM;        // [12800][2048] bf16
  u16* WvB = V   + (size_t)MROWS * CDIM;        // [2048][2048]  bf16
  u16* WcB = WvB + (size_t)CDIM * CDIM;         // [1024][2048]  bf16

  {
    int n4a = CDIM * CDIM / 4;                  // 1048576
    int n4b = ODIM * CDIM / 4;                  // 524288
    int nCvt = (n4a + n4b + 255) / 256;         // 6144
    cvt_prep_kernel<<<nCvt + BATCH * 32, 256, 0, stream>>>(
        Wv, WvB, n4a, Wc, WcB, n4b, x, pos, T, nCvt);
  }

  // GEMM1: [12800,2048]x[2048,2048]^T -> V ; grid 400 (%8==0)
  gemm256<1><<<(MROWS / 256) * (CDIM / 256), 512, 0, stream>>>(
      T, WvB, bv, V, MROWS, CDIM, CDIM, CDIM / 256);

  attn0_kernel<<<dim3(BATCH, NHEADS), 64, 0, stream>>>(V);

  // GEMM2: [12800,2048]x[1024,2048]^T -> out ; grid 200 (%8==0)
  gemm256<0><<<(MROWS / 256) * (ODIM / 256), 512, 0, stream>>>(
      V, WcB, bc, out, MROWS, ODIM, CDIM, ODIM / 256);
}